// Round 6
// baseline (539.758 us; speedup 1.0000x reference)
//
#include <hip/hip_runtime.h>
#include <math.h>

// CNF log_prob, MI355X fp32 VALU implementation.
// B=32768 rows, DIM=16, COND=64, HID=512, steps=5 (4 RK4 steps, 16 func evals).
//
// Algebraic reductions:
//   ctx_proj[r][j] = b1[j] + sum_c ctx[r][c] * W1[16+c][j]        (constant over evals)
//   dpre[r][j]     = sum_i eps[r][i] * W1[i][j]                   (constant tangent)
//   w2eps[r][j]    = sum_k W2[j][k] * eps[r][k]
//   g[r][j]        = dpre[r][j] * w2eps[r][j]
// per eval:  pre = z@W1z + t*W1t + ctx_proj ; h = tanh(pre)
//            f   = h @ W2 + b2
//            div = sum_j (1 - h_j^2) * g[r][j]
//
// LDS-pipe economy (the modeled bottleneck):
//  * z distributed via v_readlane from one b64 snapshot/eval (VALU pipe)
//  * each thread owns ADJACENT units 2t,2t+1 -> single ds_write_b64 for h
//  * phase-2 cb reduction: 1 DPP row_ror:8 add (VALU) + 4 pair-partials in
//    LDS, summed scalar in the update phase (no shfl chain on the LDS pipe)
//  * dvp pre-reduced with DPP xor8; stored flat stride-136 so the writer
//    pattern (slot dvi) and reader partition (slots k+16m) are both
//    conflict-free (write: 32 distinct banks; read: 2-way = free)

#define NTHREADS 256
#define R 8          // rows per block
#define HID 512
#define DIMZ 16
#define COND 64
#define HSTRIDE 576  // h row: phys idx = j + (j>>5)*4, max 571
#define DVSTRIDE 136 // dvp row stride (floats): write banks 8r+8q+(t&7), read 8r+k+16m

__device__ __forceinline__ float tanh_fast(float x) {
    // tanh(x) = 1 - 2/(1+exp2(x*2*log2(e))); 5 VALU ops, exact at +-inf
    float e = __builtin_amdgcn_exp2f(x * 2.885390081777927f);
    float r = __builtin_amdgcn_rcpf(1.0f + e);
    return fmaf(-2.0f, r, 1.0f);
}

// butterfly add with lane^8 partner via DPP row_ror:8 (16-lane row rotation
// by 8 == xor 8 within the row) -- VALU pipe, no LDS traffic
__device__ __forceinline__ float dpp_xor8_add(float v) {
    int p = __builtin_amdgcn_update_dpp(0, __float_as_int(v), 0x128, 0xF, 0xF, false);
    return v + __int_as_float(p);
}

#define ZRL(src, lane) __int_as_float(__builtin_amdgcn_readlane(__float_as_int(src), (lane)))

__global__ __launch_bounds__(NTHREADS, 3)
void cnf_logprob_kernel(const float* __restrict__ x,
                        const float* __restrict__ ctx,
                        const float* __restrict__ eps,
                        const float* __restrict__ W1,
                        const float* __restrict__ b1,
                        const float* __restrict__ W2,
                        const float* __restrict__ b2,
                        float* __restrict__ out)
{
    const int t    = threadIdx.x;
    const int row0 = blockIdx.x * R;
    const int u0   = 2 * t;      // owned hidden units (adjacent pair)
    const int k    = t & 15;     // update-phase column
    const int kk   = t & 7;      // phase-2 column pair {kk, kk+8}
    const int cb   = t >> 3;     // phase-2 chunk of 16 h-units
    const int cbp  = (t >> 4) & 3; // chunk-pair index after xor8 reduce
    const int wv   = t >> 6;
    const int zl   = t & 63;     // per-wave z-snapshot lane role
    const int dvi  = (t >> 4) * 8 + (t & 7);  // compressed dvp slot (t&8==0 lanes)

    __shared__ __align__(16) float ctx_lds[R][COND];   // 2 KB
    __shared__ __align__(16) float eps_lds[R][DIMZ];   // 512 B
    __shared__ __align__(16) float z_in[R][DIMZ];      // 512 B
    __shared__ __align__(16) float h_lds[R][HSTRIDE];  // 18 KB, gap-swizzled
    __shared__ float dvp[R * DVSTRIDE];                // 4.25 KB (xor8-compressed)
    __shared__ float fp[4][4][R][17];                  // 8.5 KB  (wv,cbp,r,k)

    // ---------------- load inputs to LDS / regs ----------------
    {
        const int r = t >> 6, c = t & 63;
        ctx_lds[r][c]     = ctx[(row0 + r) * COND + c];
        ctx_lds[r + 4][c] = ctx[(row0 + r + 4) * COND + c];
    }
    float zcur = 0.f, zacc = 0.f, lp = 0.f, lpa = 0.f, b2k = 0.f;
    if (t < 128) {
        const int r = t >> 4;
        zcur = x[(row0 + r) * DIMZ + k];
        z_in[r][k] = zcur;
        eps_lds[r][k] = eps[(row0 + r) * DIMZ + k];
        b2k = b2[k];
    }
    __syncthreads();

    // ---------------- precompute ----------------
    // W1z columns (rows 0..15 of W1) into regs; dpre = eps @ W1z
    float w1z0[16], w1z1[16];
    float da0[R], da1[R];
#pragma unroll
    for (int r = 0; r < R; ++r) { da0[r] = 0.f; da1[r] = 0.f; }
#pragma unroll
    for (int i = 0; i < 16; ++i) {
        const float2 wz = *reinterpret_cast<const float2*>(&W1[i * HID + u0]);
        w1z0[i] = wz.x;
        w1z1[i] = wz.y;
    }
#pragma unroll
    for (int iq = 0; iq < 4; ++iq) {
#pragma unroll
        for (int r = 0; r < R; ++r) {
            const float4 e4 = *reinterpret_cast<const float4*>(&eps_lds[r][iq * 4]);
            da0[r] += e4.x * w1z0[iq * 4 + 0] + e4.y * w1z0[iq * 4 + 1]
                    + e4.z * w1z0[iq * 4 + 2] + e4.w * w1z0[iq * 4 + 3];
            da1[r] += e4.x * w1z1[iq * 4 + 0] + e4.y * w1z1[iq * 4 + 1]
                    + e4.z * w1z1[iq * 4 + 2] + e4.w * w1z1[iq * 4 + 3];
        }
    }

    // ctx_proj = b1 + ctx @ W1[16:80]
    float c0[R], c1[R];
    {
        const float2 bb = *reinterpret_cast<const float2*>(&b1[u0]);
#pragma unroll
        for (int r = 0; r < R; ++r) { c0[r] = bb.x; c1[r] = bb.y; }
    }
#pragma unroll
    for (int iq = 0; iq < 16; ++iq) {
        float wa[4], wb[4];
#pragma unroll
        for (int m = 0; m < 4; ++m) {
            const float2 wz = *reinterpret_cast<const float2*>(&W1[(16 + iq * 4 + m) * HID + u0]);
            wa[m] = wz.x;
            wb[m] = wz.y;
        }
#pragma unroll
        for (int r = 0; r < R; ++r) {
            const float4 cv = *reinterpret_cast<const float4*>(&ctx_lds[r][iq * 4]);
            c0[r] += cv.x * wa[0] + cv.y * wa[1] + cv.z * wa[2] + cv.w * wa[3];
            c1[r] += cv.x * wb[0] + cv.y * wb[1] + cv.z * wb[2] + cv.w * wb[3];
        }
    }

    const float2 w1tv = *reinterpret_cast<const float2*>(&W1[80 * HID + u0]);
    const float w1t0 = w1tv.x;
    const float w1t1 = w1tv.y;

    // g = dpre * (W2 row . eps)
    float g0[R], g1[R];
    {
        const float4 wa0 = *reinterpret_cast<const float4*>(&W2[u0 * 16 + 0]);
        const float4 wa1 = *reinterpret_cast<const float4*>(&W2[u0 * 16 + 4]);
        const float4 wa2 = *reinterpret_cast<const float4*>(&W2[u0 * 16 + 8]);
        const float4 wa3 = *reinterpret_cast<const float4*>(&W2[u0 * 16 + 12]);
        const float4 wb0 = *reinterpret_cast<const float4*>(&W2[u0 * 16 + 16]);
        const float4 wb1 = *reinterpret_cast<const float4*>(&W2[u0 * 16 + 20]);
        const float4 wb2 = *reinterpret_cast<const float4*>(&W2[u0 * 16 + 24]);
        const float4 wb3 = *reinterpret_cast<const float4*>(&W2[u0 * 16 + 28]);
#pragma unroll
        for (int r = 0; r < R; ++r) {
            const float4 e0 = *reinterpret_cast<const float4*>(&eps_lds[r][0]);
            const float4 e1 = *reinterpret_cast<const float4*>(&eps_lds[r][4]);
            const float4 e2 = *reinterpret_cast<const float4*>(&eps_lds[r][8]);
            const float4 e3 = *reinterpret_cast<const float4*>(&eps_lds[r][12]);
            const float s0 = wa0.x * e0.x + wa0.y * e0.y + wa0.z * e0.z + wa0.w * e0.w
                           + wa1.x * e1.x + wa1.y * e1.y + wa1.z * e1.z + wa1.w * e1.w
                           + wa2.x * e2.x + wa2.y * e2.y + wa2.z * e2.z + wa2.w * e2.w
                           + wa3.x * e3.x + wa3.y * e3.y + wa3.z * e3.z + wa3.w * e3.w;
            const float s1 = wb0.x * e0.x + wb0.y * e0.y + wb0.z * e0.z + wb0.w * e0.w
                           + wb1.x * e1.x + wb1.y * e1.y + wb1.z * e1.z + wb1.w * e1.w
                           + wb2.x * e2.x + wb2.y * e2.y + wb2.z * e2.z + wb2.w * e2.w
                           + wb3.x * e3.x + wb3.y * e3.y + wb3.z * e3.z + wb3.w * e3.w;
            g0[r] = da0[r] * s0;
            g1[r] = da1[r] * s1;
        }
    }

    // phase-2 W2 registers: columns kk and kk+8 for chunk cb
    float w2a[16], w2b[16];
#pragma unroll
    for (int q = 0; q < 16; ++q) {
        w2a[q] = W2[(cb * 16 + q) * 16 + kk];
        w2b[q] = W2[(cb * 16 + q) * 16 + kk + 8];
    }

    const int phys2 = 2 * t + ((t >> 4) << 2);     // phys(u0); phys(u0+1)=+1
    const int hbase = cb * 16 + ((cb >> 1) << 2);  // swizzled chunk start
    const float* z_flat = &z_in[0][0];

    // ---------------- 16 func evals (4 RK4 steps) ----------------
    for (int it = 0; it < 16; ++it) {
        const int s = it & 3;
        float tt = 1.0f - 0.25f * (float)(it >> 2);
        if (s == 1 || s == 2) tt -= 0.125f;
        else if (s == 3)      tt -= 0.25f;

        // per-eval z snapshot: one conflict-free b64 read per lane, then
        // wave-uniform access via v_readlane (VALU pipe, not LDS pipe).
        // flat z index f lives at lane f>>1, component f&1.
        const float2 zsnap = *reinterpret_cast<const float2*>(&z_flat[2 * zl]);

        // phase 1: h = tanh(z@W1z + t*W1t + ctx_proj); div partials
#pragma unroll
        for (int r = 0; r < R; ++r) {
            float p0 = fmaf(tt, w1t0, c0[r]);
            float p1 = fmaf(tt, w1t1, c1[r]);
#pragma unroll
            for (int i = 0; i < 16; ++i) {
                const int fl = r * 16 + i;
                const float zi = (fl & 1) ? ZRL(zsnap.y, fl >> 1)
                                          : ZRL(zsnap.x, fl >> 1);
                p0 = fmaf(zi, w1z0[i], p0);
                p1 = fmaf(zi, w1z1[i], p1);
            }
            const float h0 = tanh_fast(p0);
            const float h1 = tanh_fast(p1);
            *reinterpret_cast<float2*>(&h_lds[r][phys2]) = make_float2(h0, h1);
            // dvp pre-reduced with lane^8 partner (VALU DPP), masked write
            const float dv = dpp_xor8_add((1.0f - h0 * h0) * g0[r]
                                        + (1.0f - h1 * h1) * g1[r]);
            if ((t & 8) == 0) dvp[r * DVSTRIDE + dvi] = dv;
        }
        __syncthreads();

        // phase 2: f partials = h @ W2; 2 columns per thread, 16-unit chunk.
        // Reduce cb bit 0 via DPP (VALU); pair-partials to LDS.
#pragma unroll
        for (int r = 0; r < R; ++r) {
            const float* hb = &h_lds[r][hbase];
            float pa = 0.f, pb = 0.f;
#pragma unroll
            for (int q4 = 0; q4 < 4; ++q4) {
                const float4 h4 = *reinterpret_cast<const float4*>(hb + q4 * 4);
                pa = fmaf(h4.x, w2a[q4 * 4 + 0], pa);
                pa = fmaf(h4.y, w2a[q4 * 4 + 1], pa);
                pa = fmaf(h4.z, w2a[q4 * 4 + 2], pa);
                pa = fmaf(h4.w, w2a[q4 * 4 + 3], pa);
                pb = fmaf(h4.x, w2b[q4 * 4 + 0], pb);
                pb = fmaf(h4.y, w2b[q4 * 4 + 1], pb);
                pb = fmaf(h4.z, w2b[q4 * 4 + 2], pb);
                pb = fmaf(h4.w, w2b[q4 * 4 + 3], pb);
            }
            pa = dpp_xor8_add(pa);   // + lane^8 partner (cb bit 0)
            pb = dpp_xor8_add(pb);
            if ((t & 8) == 0) {
                fp[wv][cbp][r][kk]     = pa;
                fp[wv][cbp][r][kk + 8] = pb;
            }
        }
        __syncthreads();

        // update: assemble f (16 pair-partials), reduce div, RK4 stage
        if (t < 128) {
            const int r = t >> 4;
            float f = b2k;
#pragma unroll
            for (int wvq = 0; wvq < 4; ++wvq)
#pragma unroll
                for (int cq = 0; cq < 4; ++cq)
                    f += fp[wvq][cq][r][k];
            // read partition: lane k sums slots {k+16m} (any partition works;
            // this one is 2-way-bank = free on the read, vs 8-way for k*8+m)
            float dsum = 0.f;
#pragma unroll
            for (int m = 0; m < 8; ++m) dsum += dvp[r * DVSTRIDE + k + 16 * m];
            dsum += __shfl_xor(dsum, 1);
            dsum += __shfl_xor(dsum, 2);
            dsum += __shfl_xor(dsum, 4);
            dsum += __shfl_xor(dsum, 8);

            float znew;
            if (s == 0) {
                zacc = f;            lpa = dsum;
                znew = fmaf(-0.125f, f, zcur);
            } else if (s == 1) {
                zacc += 2.f * f;     lpa += 2.f * dsum;
                znew = fmaf(-0.125f, f, zcur);
            } else if (s == 2) {
                zacc += 2.f * f;     lpa += 2.f * dsum;
                znew = fmaf(-0.25f, f, zcur);
            } else {
                zacc += f;           lpa += dsum;
                zcur = fmaf(-0.25f / 6.0f, zacc, zcur);   // dt/6, dt = -0.25
                lp   = fmaf( 0.25f / 6.0f, lpa,  lp);     // lp += -(dt/6)*sum(div)
                znew = zcur;
            }
            z_in[r][k] = znew;
        }
        __syncthreads();
    }

    // ---------------- epilogue: base logprob + delta ----------------
    if (t < 128) {
        const int r = t >> 4;
        float s2 = zcur * zcur;
        s2 += __shfl_xor(s2, 1);
        s2 += __shfl_xor(s2, 2);
        s2 += __shfl_xor(s2, 4);
        s2 += __shfl_xor(s2, 8);
        if (k == 0)
            out[row0 + r] = fmaf(-0.5f, s2, lp - 14.7030165312747625f);
    }
}

extern "C" void kernel_launch(void* const* d_in, const int* in_sizes, int n_in,
                              void* d_out, int out_size, void* d_ws, size_t ws_size,
                              hipStream_t stream) {
    const float* x    = (const float*)d_in[0];
    const float* ctx  = (const float*)d_in[1];
    const float* eps  = (const float*)d_in[2];
    const float* W1   = (const float*)d_in[3];
    const float* b1   = (const float*)d_in[4];
    const float* W2   = (const float*)d_in[5];
    const float* b2   = (const float*)d_in[6];
    // d_in[7] = steps (fixed at 5 -> 4 RK4 steps, hardcoded)
    float* out = (float*)d_out;

    const int B = in_sizes[0] / DIMZ;      // 32768
    const int nblocks = B / R;             // 4096

    hipLaunchKernelGGL(cnf_logprob_kernel, dim3(nblocks), dim3(NTHREADS), 0, stream,
                       x, ctx, eps, W1, b1, W2, b2, out);
}

// Round 7
// 490.693 us; speedup vs baseline: 1.1000x; 1.1000x over previous
//
#include <hip/hip_runtime.h>
#include <math.h>

// CNF log_prob, MI355X fp32 VALU implementation.
// B=32768 rows, DIM=16, COND=64, HID=512, steps=5 (4 RK4 steps, 16 func evals).
//
// Algebraic reductions:
//   ctx_proj[r][j] = b1[j] + sum_c ctx[r][c] * W1[16+c][j]        (constant over evals)
//   dpre[r][j]     = sum_i eps[r][i] * W1[i][j]                   (constant tangent)
//   w2eps[r][j]    = sum_k W2[j][k] * eps[r][k]
//   g[r][j]        = dpre[r][j] * w2eps[r][j]
// per eval:  pre = z@W1z + t*W1t + ctx_proj ; h = tanh(pre)
//            f   = h @ W2 + b2
//            div = sum_j (1 - h_j^2) * g[r][j]
//
// R6 lessons (first real counters): VALU-issue-bound (91% busy), NOT LDS-bound;
// VGPR_Count=84 + WRITE_SIZE=278MB proved the compiler spilled the register
// arrays chasing occupancy that LDS caps anyway. Fixes:
//  * amdgpu_waves_per_eu(3,3): pin 3 waves/EU -> ~168 VGPR budget, no spills
//  * z distributed via broadcast ds_read_b128 (LDS pipe has headroom), not
//    v_readlane chains (2048 VALU instrs/thread removed)
//  * keep: DPP xor8 reductions (VALU but cheap), dvp compression, bank-clean
//    layouts (6.3M conflict-cycles measured ~= 10us, negligible)

#define NTHREADS 256
#define R 8          // rows per block
#define HID 512
#define DIMZ 16
#define COND 64
#define HSTRIDE 576  // h row: phys idx = j + (j>>5)*4, max 571
#define DVSTRIDE 136 // dvp row stride (floats): write banks 8r+8q+(t&7), read 8r+k+16m

__device__ __forceinline__ float tanh_fast(float x) {
    // tanh(x) = 1 - 2/(1+exp2(x*2*log2(e))); 5 VALU ops, exact at +-inf
    float e = __builtin_amdgcn_exp2f(x * 2.885390081777927f);
    float r = __builtin_amdgcn_rcpf(1.0f + e);
    return fmaf(-2.0f, r, 1.0f);
}

// butterfly add with lane^8 partner via DPP row_ror:8 (16-lane row rotation
// by 8 == xor 8 within the row) -- VALU pipe, no LDS traffic
__device__ __forceinline__ float dpp_xor8_add(float v) {
    int p = __builtin_amdgcn_update_dpp(0, __float_as_int(v), 0x128, 0xF, 0xF, false);
    return v + __int_as_float(p);
}

__global__ __launch_bounds__(NTHREADS)
__attribute__((amdgpu_waves_per_eu(3, 3)))
void cnf_logprob_kernel(const float* __restrict__ x,
                        const float* __restrict__ ctx,
                        const float* __restrict__ eps,
                        const float* __restrict__ W1,
                        const float* __restrict__ b1,
                        const float* __restrict__ W2,
                        const float* __restrict__ b2,
                        float* __restrict__ out)
{
    const int t    = threadIdx.x;
    const int row0 = blockIdx.x * R;
    const int u0   = 2 * t;      // owned hidden units (adjacent pair)
    const int k    = t & 15;     // update-phase column
    const int kk   = t & 7;      // phase-2 column pair {kk, kk+8}
    const int cb   = t >> 3;     // phase-2 chunk of 16 h-units
    const int cbp  = (t >> 4) & 3; // chunk-pair index after xor8 reduce
    const int wv   = t >> 6;
    const int dvi  = (t >> 4) * 8 + (t & 7);  // compressed dvp slot (t&8==0 lanes)

    __shared__ __align__(16) float ctx_lds[R][COND];   // 2 KB
    __shared__ __align__(16) float eps_lds[R][DIMZ];   // 512 B
    __shared__ __align__(16) float z_in[R][DIMZ];      // 512 B
    __shared__ __align__(16) float h_lds[R][HSTRIDE];  // 18 KB, gap-swizzled
    __shared__ float dvp[R * DVSTRIDE];                // 4.25 KB (xor8-compressed)
    __shared__ float fp[4][4][R][17];                  // 8.5 KB  (wv,cbp,r,k)

    // ---------------- load inputs to LDS / regs ----------------
    {
        const int r = t >> 6, c = t & 63;
        ctx_lds[r][c]     = ctx[(row0 + r) * COND + c];
        ctx_lds[r + 4][c] = ctx[(row0 + r + 4) * COND + c];
    }
    float zcur = 0.f, zacc = 0.f, lp = 0.f, lpa = 0.f, b2k = 0.f;
    if (t < 128) {
        const int r = t >> 4;
        zcur = x[(row0 + r) * DIMZ + k];
        z_in[r][k] = zcur;
        eps_lds[r][k] = eps[(row0 + r) * DIMZ + k];
        b2k = b2[k];
    }
    __syncthreads();

    // ---------------- precompute ----------------
    // W1z columns (rows 0..15 of W1) into regs; dpre = eps @ W1z
    float w1z0[16], w1z1[16];
    float da0[R], da1[R];
#pragma unroll
    for (int r = 0; r < R; ++r) { da0[r] = 0.f; da1[r] = 0.f; }
#pragma unroll
    for (int i = 0; i < 16; ++i) {
        const float2 wz = *reinterpret_cast<const float2*>(&W1[i * HID + u0]);
        w1z0[i] = wz.x;
        w1z1[i] = wz.y;
    }
#pragma unroll
    for (int iq = 0; iq < 4; ++iq) {
#pragma unroll
        for (int r = 0; r < R; ++r) {
            const float4 e4 = *reinterpret_cast<const float4*>(&eps_lds[r][iq * 4]);
            da0[r] += e4.x * w1z0[iq * 4 + 0] + e4.y * w1z0[iq * 4 + 1]
                    + e4.z * w1z0[iq * 4 + 2] + e4.w * w1z0[iq * 4 + 3];
            da1[r] += e4.x * w1z1[iq * 4 + 0] + e4.y * w1z1[iq * 4 + 1]
                    + e4.z * w1z1[iq * 4 + 2] + e4.w * w1z1[iq * 4 + 3];
        }
    }

    // ctx_proj = b1 + ctx @ W1[16:80]
    float c0[R], c1[R];
    {
        const float2 bb = *reinterpret_cast<const float2*>(&b1[u0]);
#pragma unroll
        for (int r = 0; r < R; ++r) { c0[r] = bb.x; c1[r] = bb.y; }
    }
#pragma unroll
    for (int iq = 0; iq < 16; ++iq) {
        float wa[4], wb[4];
#pragma unroll
        for (int m = 0; m < 4; ++m) {
            const float2 wz = *reinterpret_cast<const float2*>(&W1[(16 + iq * 4 + m) * HID + u0]);
            wa[m] = wz.x;
            wb[m] = wz.y;
        }
#pragma unroll
        for (int r = 0; r < R; ++r) {
            const float4 cv = *reinterpret_cast<const float4*>(&ctx_lds[r][iq * 4]);
            c0[r] += cv.x * wa[0] + cv.y * wa[1] + cv.z * wa[2] + cv.w * wa[3];
            c1[r] += cv.x * wb[0] + cv.y * wb[1] + cv.z * wb[2] + cv.w * wb[3];
        }
    }

    const float2 w1tv = *reinterpret_cast<const float2*>(&W1[80 * HID + u0]);
    const float w1t0 = w1tv.x;
    const float w1t1 = w1tv.y;

    // g = dpre * (W2 row . eps)
    float g0[R], g1[R];
    {
        const float4 wa0 = *reinterpret_cast<const float4*>(&W2[u0 * 16 + 0]);
        const float4 wa1 = *reinterpret_cast<const float4*>(&W2[u0 * 16 + 4]);
        const float4 wa2 = *reinterpret_cast<const float4*>(&W2[u0 * 16 + 8]);
        const float4 wa3 = *reinterpret_cast<const float4*>(&W2[u0 * 16 + 12]);
        const float4 wb0 = *reinterpret_cast<const float4*>(&W2[u0 * 16 + 16]);
        const float4 wb1 = *reinterpret_cast<const float4*>(&W2[u0 * 16 + 20]);
        const float4 wb2 = *reinterpret_cast<const float4*>(&W2[u0 * 16 + 24]);
        const float4 wb3 = *reinterpret_cast<const float4*>(&W2[u0 * 16 + 28]);
#pragma unroll
        for (int r = 0; r < R; ++r) {
            const float4 e0 = *reinterpret_cast<const float4*>(&eps_lds[r][0]);
            const float4 e1 = *reinterpret_cast<const float4*>(&eps_lds[r][4]);
            const float4 e2 = *reinterpret_cast<const float4*>(&eps_lds[r][8]);
            const float4 e3 = *reinterpret_cast<const float4*>(&eps_lds[r][12]);
            const float s0 = wa0.x * e0.x + wa0.y * e0.y + wa0.z * e0.z + wa0.w * e0.w
                           + wa1.x * e1.x + wa1.y * e1.y + wa1.z * e1.z + wa1.w * e1.w
                           + wa2.x * e2.x + wa2.y * e2.y + wa2.z * e2.z + wa2.w * e2.w
                           + wa3.x * e3.x + wa3.y * e3.y + wa3.z * e3.z + wa3.w * e3.w;
            const float s1 = wb0.x * e0.x + wb0.y * e0.y + wb0.z * e0.z + wb0.w * e0.w
                           + wb1.x * e1.x + wb1.y * e1.y + wb1.z * e1.z + wb1.w * e1.w
                           + wb2.x * e2.x + wb2.y * e2.y + wb2.z * e2.z + wb2.w * e2.w
                           + wb3.x * e3.x + wb3.y * e3.y + wb3.z * e3.z + wb3.w * e3.w;
            g0[r] = da0[r] * s0;
            g1[r] = da1[r] * s1;
        }
    }

    // phase-2 W2 registers: columns kk and kk+8 for chunk cb
    float w2a[16], w2b[16];
#pragma unroll
    for (int q = 0; q < 16; ++q) {
        w2a[q] = W2[(cb * 16 + q) * 16 + kk];
        w2b[q] = W2[(cb * 16 + q) * 16 + kk + 8];
    }

    const int phys2 = 2 * t + ((t >> 4) << 2);     // phys(u0); phys(u0+1)=+1
    const int hbase = cb * 16 + ((cb >> 1) << 2);  // swizzled chunk start

    // ---------------- 16 func evals (4 RK4 steps) ----------------
    for (int it = 0; it < 16; ++it) {
        const int s = it & 3;
        float tt = 1.0f - 0.25f * (float)(it >> 2);
        if (s == 1 || s == 2) tt -= 0.125f;
        else if (s == 3)      tt -= 0.25f;

        // phase 1: h = tanh(z@W1z + t*W1t + ctx_proj); div partials.
        // z via broadcast ds_read_b128 (wave-uniform addr = conflict-free,
        // LDS pipe) -- the VALU pipe is the saturated one (R6 counters).
#pragma unroll
        for (int r = 0; r < R; ++r) {
            float p0 = fmaf(tt, w1t0, c0[r]);
            float p1 = fmaf(tt, w1t1, c1[r]);
#pragma unroll
            for (int iq = 0; iq < 4; ++iq) {
                const float4 z4 = *reinterpret_cast<const float4*>(&z_in[r][iq * 4]);
                p0 = fmaf(z4.x, w1z0[iq * 4 + 0], p0);
                p0 = fmaf(z4.y, w1z0[iq * 4 + 1], p0);
                p0 = fmaf(z4.z, w1z0[iq * 4 + 2], p0);
                p0 = fmaf(z4.w, w1z0[iq * 4 + 3], p0);
                p1 = fmaf(z4.x, w1z1[iq * 4 + 0], p1);
                p1 = fmaf(z4.y, w1z1[iq * 4 + 1], p1);
                p1 = fmaf(z4.z, w1z1[iq * 4 + 2], p1);
                p1 = fmaf(z4.w, w1z1[iq * 4 + 3], p1);
            }
            const float h0 = tanh_fast(p0);
            const float h1 = tanh_fast(p1);
            *reinterpret_cast<float2*>(&h_lds[r][phys2]) = make_float2(h0, h1);
            // dvp pre-reduced with lane^8 partner (VALU DPP), masked write
            const float dv = dpp_xor8_add((1.0f - h0 * h0) * g0[r]
                                        + (1.0f - h1 * h1) * g1[r]);
            if ((t & 8) == 0) dvp[r * DVSTRIDE + dvi] = dv;
        }
        __syncthreads();

        // phase 2: f partials = h @ W2; 2 columns per thread, 16-unit chunk.
        // Reduce cb bit 0 via DPP (VALU); pair-partials to LDS.
#pragma unroll
        for (int r = 0; r < R; ++r) {
            const float* hb = &h_lds[r][hbase];
            float pa = 0.f, pb = 0.f;
#pragma unroll
            for (int q4 = 0; q4 < 4; ++q4) {
                const float4 h4 = *reinterpret_cast<const float4*>(hb + q4 * 4);
                pa = fmaf(h4.x, w2a[q4 * 4 + 0], pa);
                pa = fmaf(h4.y, w2a[q4 * 4 + 1], pa);
                pa = fmaf(h4.z, w2a[q4 * 4 + 2], pa);
                pa = fmaf(h4.w, w2a[q4 * 4 + 3], pa);
                pb = fmaf(h4.x, w2b[q4 * 4 + 0], pb);
                pb = fmaf(h4.y, w2b[q4 * 4 + 1], pb);
                pb = fmaf(h4.z, w2b[q4 * 4 + 2], pb);
                pb = fmaf(h4.w, w2b[q4 * 4 + 3], pb);
            }
            pa = dpp_xor8_add(pa);   // + lane^8 partner (cb bit 0)
            pb = dpp_xor8_add(pb);
            if ((t & 8) == 0) {
                fp[wv][cbp][r][kk]     = pa;
                fp[wv][cbp][r][kk + 8] = pb;
            }
        }
        __syncthreads();

        // update: assemble f (16 pair-partials), reduce div, RK4 stage
        if (t < 128) {
            const int r = t >> 4;
            float f = b2k;
#pragma unroll
            for (int wvq = 0; wvq < 4; ++wvq)
#pragma unroll
                for (int cq = 0; cq < 4; ++cq)
                    f += fp[wvq][cq][r][k];
            // read partition: lane k sums slots {k+16m} (2-way bank = free)
            float dsum = 0.f;
#pragma unroll
            for (int m = 0; m < 8; ++m) dsum += dvp[r * DVSTRIDE + k + 16 * m];
            dsum += __shfl_xor(dsum, 1);
            dsum += __shfl_xor(dsum, 2);
            dsum += __shfl_xor(dsum, 4);
            dsum += __shfl_xor(dsum, 8);

            float znew;
            if (s == 0) {
                zacc = f;            lpa = dsum;
                znew = fmaf(-0.125f, f, zcur);
            } else if (s == 1) {
                zacc += 2.f * f;     lpa += 2.f * dsum;
                znew = fmaf(-0.125f, f, zcur);
            } else if (s == 2) {
                zacc += 2.f * f;     lpa += 2.f * dsum;
                znew = fmaf(-0.25f, f, zcur);
            } else {
                zacc += f;           lpa += dsum;
                zcur = fmaf(-0.25f / 6.0f, zacc, zcur);   // dt/6, dt = -0.25
                lp   = fmaf( 0.25f / 6.0f, lpa,  lp);     // lp += -(dt/6)*sum(div)
                znew = zcur;
            }
            z_in[r][k] = znew;
        }
        __syncthreads();
    }

    // ---------------- epilogue: base logprob + delta ----------------
    if (t < 128) {
        const int r = t >> 4;
        float s2 = zcur * zcur;
        s2 += __shfl_xor(s2, 1);
        s2 += __shfl_xor(s2, 2);
        s2 += __shfl_xor(s2, 4);
        s2 += __shfl_xor(s2, 8);
        if (k == 0)
            out[row0 + r] = fmaf(-0.5f, s2, lp - 14.7030165312747625f);
    }
}

extern "C" void kernel_launch(void* const* d_in, const int* in_sizes, int n_in,
                              void* d_out, int out_size, void* d_ws, size_t ws_size,
                              hipStream_t stream) {
    const float* x    = (const float*)d_in[0];
    const float* ctx  = (const float*)d_in[1];
    const float* eps  = (const float*)d_in[2];
    const float* W1   = (const float*)d_in[3];
    const float* b1   = (const float*)d_in[4];
    const float* W2   = (const float*)d_in[5];
    const float* b2   = (const float*)d_in[6];
    // d_in[7] = steps (fixed at 5 -> 4 RK4 steps, hardcoded)
    float* out = (float*)d_out;

    const int B = in_sizes[0] / DIMZ;      // 32768
    const int nblocks = B / R;             // 4096

    hipLaunchKernelGGL(cnf_logprob_kernel, dim3(nblocks), dim3(NTHREADS), 0, stream,
                       x, ctx, eps, W1, b1, W2, b2, out);
}

// Round 8
// 428.945 us; speedup vs baseline: 1.2583x; 1.1440x over previous
//
#include <hip/hip_runtime.h>
#include <math.h>

// CNF log_prob, MI355X fp32 VALU implementation.
// B=32768 rows, DIM=16, COND=64, HID=512, steps=5 (4 RK4 steps, 16 func evals).
//
// Algebraic reductions:
//   ctx_proj[r][j] = b1[j] + sum_c ctx[r][c] * W1[16+c][j]        (constant over evals)
//   dpre[r][j]     = sum_i eps[r][i] * W1[i][j]                   (constant tangent)
//   w2eps[r][j]    = sum_k W2[j][k] * eps[r][k]
//   g[r][j]        = dpre[r][j] * w2eps[r][j]
// per eval:  pre = z@W1z + t*W1t + ctx_proj ; h = tanh(pre)
//            f   = h @ W2 + b2
//            div = sum_j (1 - h_j^2) * g[r][j]
//
// R7 lesson: local ARRAYS (w1z[16], w2a[16], c0[8]...) indexed by loop vars
// are not promoted by SROA (runs before unrolling) -> scratch/movrel path:
// VGPR=84, WRITE_SIZE=278MB, VALUBusy 90% of phantom work. Fix: macro-unroll
// everything into NAMED SCALARS (literal indices at parse time). No semantic
// change vs the absmax=0.0-validated R7 kernel.

#define NTHREADS 256
#define R 8          // rows per block
#define HID 512
#define DIMZ 16
#define COND 64
#define HSTRIDE 576  // h row: phys idx = j + (j>>5)*4, max 571
#define DVSTRIDE 136 // dvp row stride: write banks 8r+8q+(t&7), read 8r+k+16m

__device__ __forceinline__ float tanh_fast(float x) {
    // tanh(x) = 1 - 2/(1+exp2(x*2*log2(e))); 5 VALU ops, exact at +-inf
    float e = __builtin_amdgcn_exp2f(x * 2.885390081777927f);
    float r = __builtin_amdgcn_rcpf(1.0f + e);
    return fmaf(-2.0f, r, 1.0f);
}

// butterfly add with lane^8 partner via DPP row_ror:8 (16-lane row rotation
// by 8 == xor 8 within the row) -- VALU pipe, no LDS traffic
__device__ __forceinline__ float dpp_xor8_add(float v) {
    int p = __builtin_amdgcn_update_dpp(0, __float_as_int(v), 0x128, 0xF, 0xF, false);
    return v + __int_as_float(p);
}

// ---- macro unrollers (literal indices => SROA-friendly named scalars) ----
#define R8(M) M(0) M(1) M(2) M(3) M(4) M(5) M(6) M(7)
#define Q16(M) M(0) M(1) M(2) M(3) M(4) M(5) M(6) M(7) \
               M(8) M(9) M(10) M(11) M(12) M(13) M(14) M(15)

// dst += <v0..v3 (4x float4)> . <W_0..W_15 (named scalars)>
#define DOT16V(dst, W, v0, v1, v2, v3) \
    dst = fmaf(v0.x, W##_0,  dst); dst = fmaf(v0.y, W##_1,  dst); \
    dst = fmaf(v0.z, W##_2,  dst); dst = fmaf(v0.w, W##_3,  dst); \
    dst = fmaf(v1.x, W##_4,  dst); dst = fmaf(v1.y, W##_5,  dst); \
    dst = fmaf(v1.z, W##_6,  dst); dst = fmaf(v1.w, W##_7,  dst); \
    dst = fmaf(v2.x, W##_8,  dst); dst = fmaf(v2.y, W##_9,  dst); \
    dst = fmaf(v2.z, W##_10, dst); dst = fmaf(v2.w, W##_11, dst); \
    dst = fmaf(v3.x, W##_12, dst); dst = fmaf(v3.y, W##_13, dst); \
    dst = fmaf(v3.z, W##_14, dst); dst = fmaf(v3.w, W##_15, dst);

__global__ __launch_bounds__(NTHREADS)
__attribute__((amdgpu_waves_per_eu(3, 3)))
void cnf_logprob_kernel(const float* __restrict__ x,
                        const float* __restrict__ ctx,
                        const float* __restrict__ eps,
                        const float* __restrict__ W1,
                        const float* __restrict__ b1,
                        const float* __restrict__ W2,
                        const float* __restrict__ b2,
                        float* __restrict__ out)
{
    const int t    = threadIdx.x;
    const int row0 = blockIdx.x * R;
    const int u0   = 2 * t;      // owned hidden units (adjacent pair)
    const int k    = t & 15;     // update-phase column
    const int kk   = t & 7;      // phase-2 column pair {kk, kk+8}
    const int cb   = t >> 3;     // phase-2 chunk of 16 h-units
    const int cbp  = (t >> 4) & 3; // chunk-pair index after xor8 reduce
    const int wv   = t >> 6;
    const int dvi  = (t >> 4) * 8 + (t & 7);  // compressed dvp slot (t&8==0 lanes)

    __shared__ __align__(16) float ctx_lds[R][COND];   // 2 KB
    __shared__ __align__(16) float eps_lds[R][DIMZ];   // 512 B
    __shared__ __align__(16) float z_in[R][DIMZ];      // 512 B
    __shared__ __align__(16) float h_lds[R][HSTRIDE];  // 18 KB, gap-swizzled
    __shared__ float dvp[R * DVSTRIDE];                // 4.25 KB (xor8-compressed)
    __shared__ float fp[4][4][R][17];                  // 8.5 KB  (wv,cbp,r,k)

    // ---------------- load inputs to LDS / regs ----------------
    {
        const int r = t >> 6, c = t & 63;
        ctx_lds[r][c]     = ctx[(row0 + r) * COND + c];
        ctx_lds[r + 4][c] = ctx[(row0 + r + 4) * COND + c];
    }
    float zcur = 0.f, zacc = 0.f, lp = 0.f, lpa = 0.f, b2k = 0.f;
    if (t < 128) {
        const int r = t >> 4;
        zcur = x[(row0 + r) * DIMZ + k];
        z_in[r][k] = zcur;
        eps_lds[r][k] = eps[(row0 + r) * DIMZ + k];
        b2k = b2[k];
    }
    __syncthreads();

    // ---------------- precompute (all state = named scalars) ----------------
#define DECL_W1Z(i) float w1z0_##i, w1z1_##i;
    Q16(DECL_W1Z)
#define LOAD_W1Z(i) { const float2 wz = *reinterpret_cast<const float2*>(&W1[i * HID + u0]); \
                      w1z0_##i = wz.x; w1z1_##i = wz.y; }
    Q16(LOAD_W1Z)

    // ctx_proj = b1 + ctx @ W1[16:80]
#define DECL_C(r) float c0_##r, c1_##r;
    R8(DECL_C)
    {
        const float2 bb = *reinterpret_cast<const float2*>(&b1[u0]);
#define INIT_C(r) c0_##r = bb.x; c1_##r = bb.y;
        R8(INIT_C)
    }
    for (int iq = 0; iq < 16; ++iq) {
        const float2 q0 = *reinterpret_cast<const float2*>(&W1[(16 + iq * 4 + 0) * HID + u0]);
        const float2 q1 = *reinterpret_cast<const float2*>(&W1[(16 + iq * 4 + 1) * HID + u0]);
        const float2 q2 = *reinterpret_cast<const float2*>(&W1[(16 + iq * 4 + 2) * HID + u0]);
        const float2 q3 = *reinterpret_cast<const float2*>(&W1[(16 + iq * 4 + 3) * HID + u0]);
#define CTX_ROW(r) { const float4 cv = *reinterpret_cast<const float4*>(&ctx_lds[r][iq * 4]); \
        c0_##r += cv.x * q0.x + cv.y * q1.x + cv.z * q2.x + cv.w * q3.x; \
        c1_##r += cv.x * q0.y + cv.y * q1.y + cv.z * q2.y + cv.w * q3.y; }
        R8(CTX_ROW)
    }

    const float2 w1tv = *reinterpret_cast<const float2*>(&W1[80 * HID + u0]);
    const float w1t0 = w1tv.x;
    const float w1t1 = w1tv.y;

    // g = dpre * (W2 row . eps)   (dpre = eps @ W1z, folded per row)
#define DECL_G(r) float g0_##r, g1_##r;
    R8(DECL_G)
    {
        const float4 wa0 = *reinterpret_cast<const float4*>(&W2[u0 * 16 + 0]);
        const float4 wa1 = *reinterpret_cast<const float4*>(&W2[u0 * 16 + 4]);
        const float4 wa2 = *reinterpret_cast<const float4*>(&W2[u0 * 16 + 8]);
        const float4 wa3 = *reinterpret_cast<const float4*>(&W2[u0 * 16 + 12]);
        const float4 wb0 = *reinterpret_cast<const float4*>(&W2[u0 * 16 + 16]);
        const float4 wb1 = *reinterpret_cast<const float4*>(&W2[u0 * 16 + 20]);
        const float4 wb2 = *reinterpret_cast<const float4*>(&W2[u0 * 16 + 24]);
        const float4 wb3 = *reinterpret_cast<const float4*>(&W2[u0 * 16 + 28]);
#define G_ROW(r) { \
        const float4 e0 = *reinterpret_cast<const float4*>(&eps_lds[r][0]); \
        const float4 e1 = *reinterpret_cast<const float4*>(&eps_lds[r][4]); \
        const float4 e2 = *reinterpret_cast<const float4*>(&eps_lds[r][8]); \
        const float4 e3 = *reinterpret_cast<const float4*>(&eps_lds[r][12]); \
        float d0 = 0.f, d1 = 0.f; \
        DOT16V(d0, w1z0, e0, e1, e2, e3) \
        DOT16V(d1, w1z1, e0, e1, e2, e3) \
        const float s0 = wa0.x*e0.x + wa0.y*e0.y + wa0.z*e0.z + wa0.w*e0.w \
                       + wa1.x*e1.x + wa1.y*e1.y + wa1.z*e1.z + wa1.w*e1.w \
                       + wa2.x*e2.x + wa2.y*e2.y + wa2.z*e2.z + wa2.w*e2.w \
                       + wa3.x*e3.x + wa3.y*e3.y + wa3.z*e3.z + wa3.w*e3.w; \
        const float s1 = wb0.x*e0.x + wb0.y*e0.y + wb0.z*e0.z + wb0.w*e0.w \
                       + wb1.x*e1.x + wb1.y*e1.y + wb1.z*e1.z + wb1.w*e1.w \
                       + wb2.x*e2.x + wb2.y*e2.y + wb2.z*e2.z + wb2.w*e2.w \
                       + wb3.x*e3.x + wb3.y*e3.y + wb3.z*e3.z + wb3.w*e3.w; \
        g0_##r = d0 * s0; \
        g1_##r = d1 * s1; }
        R8(G_ROW)
    }

    // phase-2 W2 columns kk and kk+8 for chunk cb
#define DECL_W2C(q) float w2a_##q, w2b_##q;
    Q16(DECL_W2C)
#define LOAD_W2C(q) w2a_##q = W2[(cb * 16 + q) * 16 + kk]; \
                    w2b_##q = W2[(cb * 16 + q) * 16 + kk + 8];
    Q16(LOAD_W2C)

    const int phys2 = 2 * t + ((t >> 4) << 2);     // phys(u0); phys(u0+1)=+1
    const int hbase = cb * 16 + ((cb >> 1) << 2);  // swizzled chunk start

    // ---------------- 16 func evals (4 RK4 steps) ----------------
    for (int it = 0; it < 16; ++it) {
        const int s = it & 3;
        float tt = 1.0f - 0.25f * (float)(it >> 2);
        if (s == 1 || s == 2) tt -= 0.125f;
        else if (s == 3)      tt -= 0.25f;

        // phase 1: h = tanh(z@W1z + t*W1t + ctx_proj); div partials.
        // z via broadcast ds_read_b128 (wave-uniform = conflict-free).
#define P1_ROW(r) { \
        const float4 z0 = *reinterpret_cast<const float4*>(&z_in[r][0]); \
        const float4 z1 = *reinterpret_cast<const float4*>(&z_in[r][4]); \
        const float4 z2 = *reinterpret_cast<const float4*>(&z_in[r][8]); \
        const float4 z3 = *reinterpret_cast<const float4*>(&z_in[r][12]); \
        float p0 = fmaf(tt, w1t0, c0_##r); \
        float p1 = fmaf(tt, w1t1, c1_##r); \
        DOT16V(p0, w1z0, z0, z1, z2, z3) \
        DOT16V(p1, w1z1, z0, z1, z2, z3) \
        const float h0 = tanh_fast(p0); \
        const float h1 = tanh_fast(p1); \
        *reinterpret_cast<float2*>(&h_lds[r][phys2]) = make_float2(h0, h1); \
        const float m0 = h0 * h0, m1 = h1 * h1; \
        const float dv = dpp_xor8_add(fmaf(-m0, g0_##r, g0_##r) + fmaf(-m1, g1_##r, g1_##r)); \
        if ((t & 8) == 0) dvp[r * DVSTRIDE + dvi] = dv; }
        R8(P1_ROW)
        __syncthreads();

        // phase 2: f partials = h @ W2; 2 columns per thread, 16-unit chunk.
#define P2_ROW(r) { \
        const float* hb = &h_lds[r][hbase]; \
        const float4 h0v = *reinterpret_cast<const float4*>(hb + 0); \
        const float4 h1v = *reinterpret_cast<const float4*>(hb + 4); \
        const float4 h2v = *reinterpret_cast<const float4*>(hb + 8); \
        const float4 h3v = *reinterpret_cast<const float4*>(hb + 12); \
        float pa = 0.f, pb = 0.f; \
        DOT16V(pa, w2a, h0v, h1v, h2v, h3v) \
        DOT16V(pb, w2b, h0v, h1v, h2v, h3v) \
        pa = dpp_xor8_add(pa); \
        pb = dpp_xor8_add(pb); \
        if ((t & 8) == 0) { fp[wv][cbp][r][kk] = pa; fp[wv][cbp][r][kk + 8] = pb; } }
        R8(P2_ROW)
        __syncthreads();

        // update: assemble f (16 pair-partials), reduce div, RK4 stage
        if (t < 128) {
            const int r = t >> 4;
            float f = b2k;
#pragma unroll
            for (int wvq = 0; wvq < 4; ++wvq)
#pragma unroll
                for (int cq = 0; cq < 4; ++cq)
                    f += fp[wvq][cq][r][k];
            // read partition: lane k sums slots {k+16m} (2-way bank = free)
            float dsum = 0.f;
#pragma unroll
            for (int m = 0; m < 8; ++m) dsum += dvp[r * DVSTRIDE + k + 16 * m];
            dsum += __shfl_xor(dsum, 1);
            dsum += __shfl_xor(dsum, 2);
            dsum += __shfl_xor(dsum, 4);
            dsum += __shfl_xor(dsum, 8);

            float znew;
            if (s == 0) {
                zacc = f;            lpa = dsum;
                znew = fmaf(-0.125f, f, zcur);
            } else if (s == 1) {
                zacc += 2.f * f;     lpa += 2.f * dsum;
                znew = fmaf(-0.125f, f, zcur);
            } else if (s == 2) {
                zacc += 2.f * f;     lpa += 2.f * dsum;
                znew = fmaf(-0.25f, f, zcur);
            } else {
                zacc += f;           lpa += dsum;
                zcur = fmaf(-0.25f / 6.0f, zacc, zcur);   // dt/6, dt = -0.25
                lp   = fmaf( 0.25f / 6.0f, lpa,  lp);     // lp += -(dt/6)*sum(div)
                znew = zcur;
            }
            z_in[r][k] = znew;
        }
        __syncthreads();
    }

    // ---------------- epilogue: base logprob + delta ----------------
    if (t < 128) {
        const int r = t >> 4;
        float s2 = zcur * zcur;
        s2 += __shfl_xor(s2, 1);
        s2 += __shfl_xor(s2, 2);
        s2 += __shfl_xor(s2, 4);
        s2 += __shfl_xor(s2, 8);
        if (k == 0)
            out[row0 + r] = fmaf(-0.5f, s2, lp - 14.7030165312747625f);
    }
}

extern "C" void kernel_launch(void* const* d_in, const int* in_sizes, int n_in,
                              void* d_out, int out_size, void* d_ws, size_t ws_size,
                              hipStream_t stream) {
    const float* x    = (const float*)d_in[0];
    const float* ctx  = (const float*)d_in[1];
    const float* eps  = (const float*)d_in[2];
    const float* W1   = (const float*)d_in[3];
    const float* b1   = (const float*)d_in[4];
    const float* W2   = (const float*)d_in[5];
    const float* b2   = (const float*)d_in[6];
    // d_in[7] = steps (fixed at 5 -> 4 RK4 steps, hardcoded)
    float* out = (float*)d_out;

    const int B = in_sizes[0] / DIMZ;      // 32768
    const int nblocks = B / R;             // 4096

    hipLaunchKernelGGL(cnf_logprob_kernel, dim3(nblocks), dim3(NTHREADS), 0, stream,
                       x, ctx, eps, W1, b1, W2, b2, out);
}